// Round 1
// baseline (486.010 us; speedup 1.0000x reference)
//
#include <hip/hip_runtime.h>

// PositionwisePairFeedForward on MI355X (gfx950), round 1: correctness-first
// fp16-MFMA pipeline. Flash-style attention (no 8192^2 score materialization).
//
// Fragment-layout robustness: A and B frags are ALWAYS loaded with the same
// assumed (lane,elem)->k map, so any within-k-block permutation of the true
// HW map cancels in the dot product. C/D layout (col=lane&15,
// row=(lane>>4)*4+reg) is the HW-verified one.

typedef _Float16 f16;
typedef _Float16 h8_t __attribute__((ext_vector_type(8)));
typedef _Float16 h4_t __attribute__((ext_vector_type(4)));
typedef float    f4_t __attribute__((ext_vector_type(4)));
typedef unsigned int u4_t __attribute__((ext_vector_type(4)));

#define LOG2E 1.4426950408889634f

// ---------------------------------------------------------------- cvt f32->f16
__global__ __launch_bounds__(256)
void cvt_f32_f16(const float* __restrict__ s, f16* __restrict__ d, int n4)
{
    int i = blockIdx.x * 256 + threadIdx.x;
    if (i >= n4) return;
    f4_t v = ((const f4_t*)s)[i];
    h4_t h;
    h[0] = (f16)v[0]; h[1] = (f16)v[1]; h[2] = (f16)v[2]; h[3] = (f16)v[3];
    ((h4_t*)d)[i] = h;
}

// ------------------------------------------------- transpose anchor -> Vt f16
// src f32 [8192][256]  ->  dst f16 [256][8192]
__global__ __launch_bounds__(256)
void transpose_f16(const float* __restrict__ src, f16* __restrict__ dst)
{
    __shared__ float tile[32][33];
    const int kb = blockIdx.x, db = blockIdx.y;   // key block, d block
    const int t  = threadIdx.x;
    const int ty = t >> 3, tx4 = (t & 7) * 4;
    f4_t v = *(const f4_t*)(src + (size_t)(kb * 32 + ty) * 256 + db * 32 + tx4);
    tile[ty][tx4 + 0] = v[0]; tile[ty][tx4 + 1] = v[1];
    tile[ty][tx4 + 2] = v[2]; tile[ty][tx4 + 3] = v[3];
    __syncthreads();
    // out element dst[d][key]: d = db*32+ty, key = kb*32+tx4+j = src[key][d]
    h4_t h;
    h[0] = (f16)tile[tx4 + 0][ty]; h[1] = (f16)tile[tx4 + 1][ty];
    h[2] = (f16)tile[tx4 + 2][ty]; h[3] = (f16)tile[tx4 + 3][ty];
    *(h4_t*)(dst + (size_t)(db * 32 + ty) * 8192 + kb * 32 + tx4) = h;
}

// --------------------------------------------------------- C = A @ B^T + bias
// A f16 [M][K], B f16 [N][K] (row-major = B^T form), C f16 [M][N].
// ACT==1: PReLU with slope *act_a.  BM=128 BN=64 BK=32, 4 waves (2x2).
template<int ACT>
__global__ __launch_bounds__(256)
void gemm_bt(const f16* __restrict__ A, const f16* __restrict__ B,
             const float* __restrict__ bias, const float* __restrict__ act_a,
             f16* __restrict__ C, int M, int N, int K)
{
    constexpr int BM = 128, BN = 64, BK = 32, LDA = 40, LDB = 40; // +8 pad: 2-way banks
    __shared__ f16 As[BM * LDA];
    __shared__ f16 Bs[BN * LDB];
    const int t = threadIdx.x;
    const int w = t >> 6, l = t & 63, lg = l >> 4, lr = l & 15;
    const int wm = w >> 1, wn = w & 1;
    const int bm = blockIdx.x, bn = blockIdx.y;
    f4_t acc[4][2] = {};

    for (int kt = 0; kt < K; kt += BK) {
        #pragma unroll
        for (int i = 0; i < 2; i++) {                    // A tile: 128x32
            int s = t + i * 256;
            int row = s >> 2, c8 = (s & 3) * 8;
            *(u4_t*)(&As[row * LDA + c8]) =
                *(const u4_t*)(A + (size_t)(bm * BM + row) * K + kt + c8);
        }
        {                                                 // B tile: 64x32
            int row = t >> 2, c8 = (t & 3) * 8;
            *(u4_t*)(&Bs[row * LDB + c8]) =
                *(const u4_t*)(B + (size_t)(bn * BN + row) * K + kt + c8);
        }
        __syncthreads();
        h8_t af[4], bf[2];
        #pragma unroll
        for (int mf = 0; mf < 4; mf++)
            af[mf] = *(const h8_t*)(&As[(wm * 64 + mf * 16 + lr) * LDA + lg * 8]);
        #pragma unroll
        for (int nf = 0; nf < 2; nf++)
            bf[nf] = *(const h8_t*)(&Bs[(wn * 32 + nf * 16 + lr) * LDB + lg * 8]);
        #pragma unroll
        for (int mf = 0; mf < 4; mf++)
            #pragma unroll
            for (int nf = 0; nf < 2; nf++)
                acc[mf][nf] = __builtin_amdgcn_mfma_f32_16x16x32_f16(
                    af[mf], bf[nf], acc[mf][nf], 0, 0, 0);
        __syncthreads();
    }

    float av = 0.f;
    if constexpr (ACT) av = *act_a;
    #pragma unroll
    for (int mf = 0; mf < 4; mf++)
        #pragma unroll
        for (int nf = 0; nf < 2; nf++)
            #pragma unroll
            for (int r = 0; r < 4; r++) {
                int row = bm * BM + wm * 64 + mf * 16 + lg * 4 + r;
                int col = bn * BN + wn * 32 + nf * 16 + lr;
                float v = acc[mf][nf][r] + bias[col];
                if constexpr (ACT) v = v > 0.f ? v : av * v;
                C[(size_t)row * N + col] = (f16)v;
            }
}

// ------------------------------------------------------------- flash attention
// Q = ge16 [8192][256], K = ac16 [8192][256], Vt = anchor^T f16 [256][8192].
// Grid (128 q-blocks, 2 kv-halves); 256 thr = 4 waves x 16 q-rows.
// Swapped QK^T: S^T = mfma(K, Q) so each lane's P is lane-local (row = l&15).
__global__ __launch_bounds__(256)
void flash_attn(const f16* __restrict__ Q, const f16* __restrict__ Kc,
                const f16* __restrict__ Vt, float* __restrict__ Opart,
                float* __restrict__ mpart, float* __restrict__ lpart)
{
    constexpr int D = 256, BQ = 64, BK = 64, LDK = D + 8, LDV = BK + 8;
    constexpr int NK = 8192, NKV = 4096;
    __shared__ f16 Ks[BK * LDK];    // 33792 B (also used to stage Q once)
    __shared__ f16 Vts[D * LDV];    // 36864 B
    const int t = threadIdx.x, w = t >> 6, l = t & 63, lg = l >> 4, lr = l & 15;
    const int qb = blockIdx.x, hf = blockIdx.y;
    const size_t q0 = (size_t)qb * BQ;
    const int k0b = hf * NKV;

    // stage Q (64x256) into Ks, pull this wave's 16 rows into register frags
    #pragma unroll
    for (int i = 0; i < 8; i++) {
        int s = t + i * 256;
        int row = s >> 5, c8 = (s & 31) * 8;
        *(u4_t*)(&Ks[row * LDK + c8]) = *(const u4_t*)(Q + (q0 + row) * D + c8);
    }
    __syncthreads();
    h8_t qf[8];
    #pragma unroll
    for (int kt = 0; kt < 8; kt++)
        qf[kt] = *(const h8_t*)(&Ks[(w * 16 + lr) * LDK + kt * 32 + lg * 8]);
    __syncthreads();

    f4_t o[16] = {};
    float m_run = -3.0e38f, l_run = 0.f;

    for (int kv = 0; kv < NKV / BK; ++kv) {
        const int k0 = k0b + kv * BK;
        #pragma unroll
        for (int i = 0; i < 8; i++) {                     // K tile 64x256
            int s = t + i * 256;
            int row = s >> 5, c8 = (s & 31) * 8;
            *(u4_t*)(&Ks[row * LDK + c8]) =
                *(const u4_t*)(Kc + (size_t)(k0 + row) * D + c8);
        }
        #pragma unroll
        for (int i = 0; i < 8; i++) {                     // Vt tile 256x64
            int s = t + i * 256;
            int row = s >> 3, c8 = (s & 7) * 8;
            *(u4_t*)(&Vts[row * LDV + c8]) =
                *(const u4_t*)(Vt + (size_t)row * NK + k0 + c8);
        }
        __syncthreads();

        // S^T[key][qrow]: A = K rows (contig-8 k map), B = Q frags (same map)
        f4_t sa[4] = {};
        #pragma unroll
        for (int kt = 0; kt < 8; kt++)
            #pragma unroll
            for (int mf = 0; mf < 4; mf++) {
                h8_t af = *(const h8_t*)(&Ks[(mf * 16 + lr) * LDK + kt * 32 + lg * 8]);
                sa[mf] = __builtin_amdgcn_mfma_f32_16x16x32_f16(af, qf[kt], sa[mf], 0, 0, 0);
            }

        // online softmax; lane's q-row = lr, keys = 16f + 4*lg + r
        float mt = -3.0e38f;
        #pragma unroll
        for (int f = 0; f < 4; f++)
            #pragma unroll
            for (int r = 0; r < 4; r++) mt = fmaxf(mt, sa[f][r]);
        mt = fmaxf(mt, __shfl_xor(mt, 16));
        mt = fmaxf(mt, __shfl_xor(mt, 32));
        float mnew = fmaxf(m_run, mt);
        float corr = exp2f((m_run - mnew) * LOG2E);
        float p[4][4], rs = 0.f;
        #pragma unroll
        for (int f = 0; f < 4; f++)
            #pragma unroll
            for (int r = 0; r < 4; r++) {
                float e = exp2f((sa[f][r] - mnew) * LOG2E);
                p[f][r] = e; rs += e;
            }
        rs += __shfl_xor(rs, 16);
        rs += __shfl_xor(rs, 32);
        l_run = l_run * corr + rs;
        m_run = mnew;

        // pack P -> A frags (blocked map: j<4 -> key 32kb+4g+j; j>=4 -> +16)
        h8_t apv[2];
        #pragma unroll
        for (int kb = 0; kb < 2; kb++)
            #pragma unroll
            for (int j = 0; j < 8; j++)
                apv[kb][j] = (f16)p[2 * kb + (j >> 2)][j & 3];

        // per-O-row rescale factors (O rows = lg*4 + r, corr lives at lane==row)
        f4_t cv;
        #pragma unroll
        for (int r = 0; r < 4; r++) cv[r] = __shfl(corr, lg * 4 + r);

        // PV: B = V[key][d] from Vts[d][key], loaded with SAME blocked map
        #pragma unroll
        for (int nf = 0; nf < 16; nf++) {
            o[nf] *= cv;
            #pragma unroll
            for (int kb = 0; kb < 2; kb++) {
                h4_t blo = *(const h4_t*)(&Vts[(nf * 16 + lr) * LDV + kb * 32 + lg * 4]);
                h4_t bhi = *(const h4_t*)(&Vts[(nf * 16 + lr) * LDV + kb * 32 + 16 + lg * 4]);
                h8_t bf = __builtin_shufflevector(blo, bhi, 0, 1, 2, 3, 4, 5, 6, 7);
                o[nf] = __builtin_amdgcn_mfma_f32_16x16x32_f16(apv[kb], bf, o[nf], 0, 0, 0);
            }
        }
        __syncthreads();
    }

    // write unnormalized partial O + (m, l) for this KV half
    const size_t obase = (size_t)hf * NK * D;
    #pragma unroll
    for (int nf = 0; nf < 16; nf++)
        #pragma unroll
        for (int r = 0; r < 4; r++)
            Opart[obase + (q0 + w * 16 + lg * 4 + r) * D + nf * 16 + lr] = o[nf][r];
    if (l < 16) {
        mpart[(size_t)hf * NK + q0 + w * 16 + l] = m_run;
        lpart[(size_t)hf * NK + q0 + w * 16 + l] = l_run;
    }
}

// ------------------------------- combine KV-half partials, build dis_x (f16)
// dis[m][0:256]=guess, [256:512]=ge2ac, [512:768]=guess-ge2ac
__global__ __launch_bounds__(256)
void build_dis(const float* __restrict__ guess, const float* __restrict__ Op,
               const float* __restrict__ mp, const float* __restrict__ lp,
               f16* __restrict__ dis)
{
    const int m = blockIdx.x, d = threadIdx.x;
    const float m0 = mp[m], m1 = mp[8192 + m];
    const float l0 = lp[m], l1 = lp[8192 + m];
    const float M  = fmaxf(m0, m1);
    const float c0 = exp2f((m0 - M) * LOG2E);
    const float c1 = exp2f((m1 - M) * LOG2E);
    const float inv = 1.0f / (c0 * l0 + c1 * l1);
    const float num = c0 * Op[(size_t)m * 256 + d] +
                      c1 * Op[(size_t)8192 * 256 + (size_t)m * 256 + d];
    const float v = num * inv;
    const float g = guess[(size_t)m * 256 + d];
    dis[(size_t)m * 768 + d]       = (f16)g;
    dis[(size_t)m * 768 + 256 + d] = (f16)v;
    dis[(size_t)m * 768 + 512 + d] = (f16)(g - v);
}

// ------------------------------------------------------ out = h2 @ W3^T + b3
__global__ __launch_bounds__(256)
void final_dot(const f16* __restrict__ h2, const float* __restrict__ W3,
               const float* __restrict__ b3, float* __restrict__ out)
{
    const int t = threadIdx.x, w = t >> 6, l = t & 63;
    const int row = blockIdx.x * 4 + w;
    const f16* hr = h2 + (size_t)row * 128;
    float s = (float)hr[l] * W3[l] + (float)hr[64 + l] * W3[64 + l];
    #pragma unroll
    for (int m = 1; m < 64; m <<= 1) s += __shfl_xor(s, m);
    if (l == 0) out[row] = s + b3[0];
}

// ============================================================================
extern "C" void kernel_launch(void* const* d_in, const int* in_sizes, int n_in,
                              void* d_out, int out_size, void* d_ws, size_t ws_size,
                              hipStream_t stream)
{
    const float* anchor = (const float*)d_in[0];
    const float* guess  = (const float*)d_in[1];
    const float* Wa = (const float*)d_in[2];
    const float* ba = (const float*)d_in[3];
    const float* Wg = (const float*)d_in[4];
    const float* bg = (const float*)d_in[5];
    const float* W1 = (const float*)d_in[6];
    const float* b1 = (const float*)d_in[7];
    const float* a1 = (const float*)d_in[8];
    const float* W2 = (const float*)d_in[9];
    const float* b2 = (const float*)d_in[10];
    const float* a2 = (const float*)d_in[11];
    const float* W3 = (const float*)d_in[12];
    const float* b3 = (const float*)d_in[13];
    float* out = (float*)d_out;
    char* ws = (char*)d_ws;

    const size_t MB = 1u << 20;
    f16* A16  = (f16*)(ws + 0 * MB);        // anchor f16        4 MB
    f16* G16  = (f16*)(ws + 4 * MB);        // guess  f16        4 MB
    f16* GE16 = (f16*)(ws + 8 * MB);        // ge (Q)            4 MB
    f16* AC16 = (f16*)(ws + 12 * MB);       // ac (K)            4 MB
    f16* VT16 = (f16*)(ws + 16 * MB);       // anchor^T (V^T)    4 MB
    f16* WA16 = (f16*)(ws + 20 * MB);       // 128 KB
    f16* WG16 = (f16*)(ws + 21 * MB);       // 128 KB
    f16* W116 = (f16*)(ws + 22 * MB);       // 384 KB
    f16* W216 = (f16*)(ws + 23 * MB);       // 64 KB
    f16* DIS  = (f16*)(ws + 24 * MB);       // [8192][768]      12 MB
    f16* H1   = (f16*)(ws + 36 * MB);       // [8192][256]       4 MB
    f16* H2   = (f16*)(ws + 40 * MB);       // [8192][128]       2 MB
    float* OP = (float*)(ws + 42 * MB);     // 2x[8192][256] f32 16 MB
    float* MP = (float*)(ws + 58 * MB);     // 2x8192
    float* LP = (float*)(ws + 58 * MB + 65536);
    // total ~58.2 MB of d_ws

    // 1) conversions to f16
    cvt_f32_f16<<<2048, 256, 0, stream>>>(anchor, A16, 524288);
    cvt_f32_f16<<<2048, 256, 0, stream>>>(guess,  G16, 524288);
    cvt_f32_f16<<<64,   256, 0, stream>>>(Wa, WA16, 16384);
    cvt_f32_f16<<<64,   256, 0, stream>>>(Wg, WG16, 16384);
    cvt_f32_f16<<<192,  256, 0, stream>>>(W1, W116, 49152);
    cvt_f32_f16<<<32,   256, 0, stream>>>(W2, W216, 8192);
    transpose_f16<<<dim3(256, 8), 256, 0, stream>>>(anchor, VT16);

    // 2) projections
    gemm_bt<0><<<dim3(64, 4), 256, 0, stream>>>(G16, WG16, bg, nullptr, GE16, 8192, 256, 256);
    gemm_bt<0><<<dim3(64, 4), 256, 0, stream>>>(A16, WA16, ba, nullptr, AC16, 8192, 256, 256);

    // 3) flash attention (2 KV halves -> partials)
    flash_attn<<<dim3(128, 2), 256, 0, stream>>>(GE16, AC16, VT16, OP, MP, LP);

    // 4) combine + build dis_x
    build_dis<<<8192, 256, 0, stream>>>(guess, OP, MP, LP, DIS);

    // 5) MLP
    gemm_bt<1><<<dim3(64, 4), 256, 0, stream>>>(DIS, W116, b1, a1, H1, 8192, 256, 768);
    gemm_bt<1><<<dim3(64, 2), 256, 0, stream>>>(H1, W216, b2, a2, H2, 8192, 128, 256);
    final_dot<<<2048, 256, 0, stream>>>(H2, W3, b3, out);
}

// Round 2
// 214.198 us; speedup vs baseline: 2.2690x; 2.2690x over previous
//
#include <hip/hip_runtime.h>

// Round 2: flash attention with 8-way KV-slice grid (1024 blocks -> 2 blocks/CU)
// + register prefetch of next K/V tile (T14 async-stage) to hide load latency.
// Partials stored as normalized f16 O + per-slice (m,l); ws <= 54 MB via aliasing.

typedef _Float16 f16;
typedef _Float16 h8_t __attribute__((ext_vector_type(8)));
typedef _Float16 h4_t __attribute__((ext_vector_type(4)));
typedef float    f4_t __attribute__((ext_vector_type(4)));
typedef unsigned int u4_t __attribute__((ext_vector_type(4)));

#define LOG2E 1.4426950408889634f

// ---------------------------------------------------------------- cvt f32->f16
__global__ __launch_bounds__(256)
void cvt_f32_f16(const float* __restrict__ s, f16* __restrict__ d, int n4)
{
    int i = blockIdx.x * 256 + threadIdx.x;
    if (i >= n4) return;
    f4_t v = ((const f4_t*)s)[i];
    h4_t h;
    h[0] = (f16)v[0]; h[1] = (f16)v[1]; h[2] = (f16)v[2]; h[3] = (f16)v[3];
    ((h4_t*)d)[i] = h;
}

// ------------------------------------------------- transpose anchor -> Vt f16
__global__ __launch_bounds__(256)
void transpose_f16(const float* __restrict__ src, f16* __restrict__ dst)
{
    __shared__ float tile[32][33];
    const int kb = blockIdx.x, db = blockIdx.y;
    const int t  = threadIdx.x;
    const int ty = t >> 3, tx4 = (t & 7) * 4;
    f4_t v = *(const f4_t*)(src + (size_t)(kb * 32 + ty) * 256 + db * 32 + tx4);
    tile[ty][tx4 + 0] = v[0]; tile[ty][tx4 + 1] = v[1];
    tile[ty][tx4 + 2] = v[2]; tile[ty][tx4 + 3] = v[3];
    __syncthreads();
    h4_t h;
    h[0] = (f16)tile[tx4 + 0][ty]; h[1] = (f16)tile[tx4 + 1][ty];
    h[2] = (f16)tile[tx4 + 2][ty]; h[3] = (f16)tile[tx4 + 3][ty];
    *(h4_t*)(dst + (size_t)(db * 32 + ty) * 8192 + kb * 32 + tx4) = h;
}

// --------------------------------------------------------- C = A @ B^T + bias
template<int ACT>
__global__ __launch_bounds__(256)
void gemm_bt(const f16* __restrict__ A, const f16* __restrict__ B,
             const float* __restrict__ bias, const float* __restrict__ act_a,
             f16* __restrict__ C, int M, int N, int K)
{
    constexpr int BM = 128, BN = 64, BK = 32, LDA = 40, LDB = 40;
    __shared__ f16 As[BM * LDA];
    __shared__ f16 Bs[BN * LDB];
    const int t = threadIdx.x;
    const int w = t >> 6, l = t & 63, lg = l >> 4, lr = l & 15;
    const int wm = w >> 1, wn = w & 1;
    const int bm = blockIdx.x, bn = blockIdx.y;
    f4_t acc[4][2] = {};

    for (int kt = 0; kt < K; kt += BK) {
        #pragma unroll
        for (int i = 0; i < 2; i++) {
            int s = t + i * 256;
            int row = s >> 2, c8 = (s & 3) * 8;
            *(u4_t*)(&As[row * LDA + c8]) =
                *(const u4_t*)(A + (size_t)(bm * BM + row) * K + kt + c8);
        }
        {
            int row = t >> 2, c8 = (t & 3) * 8;
            *(u4_t*)(&Bs[row * LDB + c8]) =
                *(const u4_t*)(B + (size_t)(bn * BN + row) * K + kt + c8);
        }
        __syncthreads();
        h8_t af[4], bf[2];
        #pragma unroll
        for (int mf = 0; mf < 4; mf++)
            af[mf] = *(const h8_t*)(&As[(wm * 64 + mf * 16 + lr) * LDA + lg * 8]);
        #pragma unroll
        for (int nf = 0; nf < 2; nf++)
            bf[nf] = *(const h8_t*)(&Bs[(wn * 32 + nf * 16 + lr) * LDB + lg * 8]);
        #pragma unroll
        for (int mf = 0; mf < 4; mf++)
            #pragma unroll
            for (int nf = 0; nf < 2; nf++)
                acc[mf][nf] = __builtin_amdgcn_mfma_f32_16x16x32_f16(
                    af[mf], bf[nf], acc[mf][nf], 0, 0, 0);
        __syncthreads();
    }

    float av = 0.f;
    if constexpr (ACT) av = *act_a;
    #pragma unroll
    for (int mf = 0; mf < 4; mf++)
        #pragma unroll
        for (int nf = 0; nf < 2; nf++)
            #pragma unroll
            for (int r = 0; r < 4; r++) {
                int row = bm * BM + wm * 64 + mf * 16 + lg * 4 + r;
                int col = bn * BN + wn * 32 + nf * 16 + lr;
                float v = acc[mf][nf][r] + bias[col];
                if constexpr (ACT) v = v > 0.f ? v : av * v;
                C[(size_t)row * N + col] = (f16)v;
            }
}

// ------------------------------------------------------------- flash attention
// Grid (128 qb, 8 kv-slices of 1024 keys). 256 thr = 4 waves x 16 q-rows.
// Register-prefetch of next K/V tile hides global latency under compute.
__global__ __launch_bounds__(256, 2)
void flash_attn(const f16* __restrict__ Q, const f16* __restrict__ Kc,
                const f16* __restrict__ Vt, f16* __restrict__ OPN,
                float* __restrict__ mpart, float* __restrict__ lpart)
{
    constexpr int D = 256, BK = 64, LDK = D + 8, LDV = BK + 8;
    constexpr int NK = 8192, SL = 1024, NT = SL / BK;   // 16 tiles
    __shared__ f16 Ks[BK * LDK];
    __shared__ f16 Vts[D * LDV];
    const int t = threadIdx.x, w = t >> 6, l = t & 63, lg = l >> 4, lr = l & 15;
    const int qb = blockIdx.x, sl = blockIdx.y;
    const size_t q0 = (size_t)qb * 64;
    const int k0b = sl * SL;

    // stage Q (64x256) into Ks once; pull this wave's 16 rows into registers
    #pragma unroll
    for (int i = 0; i < 8; i++) {
        int s = t + i * 256;
        int row = s >> 5, c8 = (s & 31) * 8;
        *(u4_t*)(&Ks[row * LDK + c8]) = *(const u4_t*)(Q + (q0 + row) * D + c8);
    }
    __syncthreads();
    h8_t qf[8];
    #pragma unroll
    for (int kt = 0; kt < 8; kt++)
        qf[kt] = *(const h8_t*)(&Ks[(w * 16 + lr) * LDK + kt * 32 + lg * 8]);
    __syncthreads();

    // per-thread staging coordinates
    const int rK = t >> 5, cK = (t & 31) * 8;   // K tile: rows rK+8i, 16B at cK
    const int rV = t >> 3, cV = (t & 7) * 8;    // V tile: rows rV+32i, 16B at cV
    u4_t kp[8], vp[8];
    auto loadKV = [&](int kv) {
        const int k0 = k0b + kv * BK;
        #pragma unroll
        for (int i = 0; i < 8; i++)
            kp[i] = *(const u4_t*)(Kc + (size_t)(k0 + rK + 8 * i) * D + cK);
        #pragma unroll
        for (int i = 0; i < 8; i++)
            vp[i] = *(const u4_t*)(Vt + (size_t)(rV + 32 * i) * NK + k0 + cV);
    };
    auto writeKV = [&]() {
        #pragma unroll
        for (int i = 0; i < 8; i++)
            *(u4_t*)(&Ks[(rK + 8 * i) * LDK + cK]) = kp[i];
        #pragma unroll
        for (int i = 0; i < 8; i++)
            *(u4_t*)(&Vts[(rV + 32 * i) * LDV + cV]) = vp[i];
    };

    loadKV(0); writeKV();
    __syncthreads();

    f4_t o[16] = {};
    float m_run = -3.0e38f, l_run = 0.f;

    for (int kv = 0; kv < NT; ++kv) {
        if (kv + 1 < NT) loadKV(kv + 1);          // async issue; used after barrier

        // S^T = mfma(K, Q): lane's q-row = lr, keys = 16f + 4*lg + r
        f4_t sa[4] = {};
        #pragma unroll
        for (int kt = 0; kt < 8; kt++)
            #pragma unroll
            for (int mf = 0; mf < 4; mf++) {
                h8_t af = *(const h8_t*)(&Ks[(mf * 16 + lr) * LDK + kt * 32 + lg * 8]);
                sa[mf] = __builtin_amdgcn_mfma_f32_16x16x32_f16(af, qf[kt], sa[mf], 0, 0, 0);
            }

        float mt = -3.0e38f;
        #pragma unroll
        for (int f = 0; f < 4; f++)
            #pragma unroll
            for (int r = 0; r < 4; r++) mt = fmaxf(mt, sa[f][r]);
        mt = fmaxf(mt, __shfl_xor(mt, 16));
        mt = fmaxf(mt, __shfl_xor(mt, 32));
        float mnew = fmaxf(m_run, mt);
        float corr = exp2f((m_run - mnew) * LOG2E);
        float p[4][4], rs = 0.f;
        #pragma unroll
        for (int f = 0; f < 4; f++)
            #pragma unroll
            for (int r = 0; r < 4; r++) {
                float e = exp2f((sa[f][r] - mnew) * LOG2E);
                p[f][r] = e; rs += e;
            }
        rs += __shfl_xor(rs, 16);
        rs += __shfl_xor(rs, 32);
        l_run = l_run * corr + rs;
        m_run = mnew;

        h8_t apv[2];
        #pragma unroll
        for (int kb = 0; kb < 2; kb++)
            #pragma unroll
            for (int j = 0; j < 8; j++)
                apv[kb][j] = (f16)p[2 * kb + (j >> 2)][j & 3];

        f4_t cv;
        #pragma unroll
        for (int r = 0; r < 4; r++) cv[r] = __shfl(corr, lg * 4 + r);

        #pragma unroll
        for (int nf = 0; nf < 16; nf++) {
            o[nf] *= cv;
            #pragma unroll
            for (int kb = 0; kb < 2; kb++) {
                h4_t blo = *(const h4_t*)(&Vts[(nf * 16 + lr) * LDV + kb * 32 + lg * 4]);
                h4_t bhi = *(const h4_t*)(&Vts[(nf * 16 + lr) * LDV + kb * 32 + 16 + lg * 4]);
                h8_t bf = __builtin_shufflevector(blo, bhi, 0, 1, 2, 3, 4, 5, 6, 7);
                o[nf] = __builtin_amdgcn_mfma_f32_16x16x32_f16(apv[kb], bf, o[nf], 0, 0, 0);
            }
        }
        __syncthreads();                          // everyone done reading LDS
        if (kv + 1 < NT) writeKV();               // compiler waits vmcnt here
        __syncthreads();
    }

    // normalized f16 partial O + (m, l) for this slice
    f4_t linv;
    #pragma unroll
    for (int r = 0; r < 4; r++) linv[r] = 1.0f / __shfl(l_run, lg * 4 + r);
    const size_t obase = ((size_t)sl * NK + q0) * D;
    #pragma unroll
    for (int nf = 0; nf < 16; nf++)
        #pragma unroll
        for (int r = 0; r < 4; r++)
            OPN[obase + (size_t)(w * 16 + lg * 4 + r) * D + nf * 16 + lr] =
                (f16)(o[nf][r] * linv[r]);
    if (l < 16) {
        mpart[(size_t)sl * NK + q0 + w * 16 + l] = m_run;
        lpart[(size_t)sl * NK + q0 + w * 16 + l] = l_run;
    }
}

// ------------------------------- combine 8 slice partials, build dis_x (f16)
__global__ __launch_bounds__(256)
void build_dis(const float* __restrict__ guess, const f16* __restrict__ OPN,
               const float* __restrict__ mp, const float* __restrict__ lp,
               f16* __restrict__ dis)
{
    const int m = blockIdx.x, d = threadIdx.x;
    float M = -3.0e38f;
    #pragma unroll
    for (int s = 0; s < 8; s++) M = fmaxf(M, mp[s * 8192 + m]);
    float wsum = 0.f, num = 0.f;
    #pragma unroll
    for (int s = 0; s < 8; s++) {
        float c = exp2f((mp[s * 8192 + m] - M) * LOG2E) * lp[s * 8192 + m];
        wsum += c;
        num  += c * (float)OPN[((size_t)s * 8192 + m) * 256 + d];
    }
    const float v = num / wsum;
    const float g = guess[(size_t)m * 256 + d];
    dis[(size_t)m * 768 + d]       = (f16)g;
    dis[(size_t)m * 768 + 256 + d] = (f16)v;
    dis[(size_t)m * 768 + 512 + d] = (f16)(g - v);
}

// ------------------------------------------------------ out = h2 @ W3^T + b3
__global__ __launch_bounds__(256)
void final_dot(const f16* __restrict__ h2, const float* __restrict__ W3,
               const float* __restrict__ b3, float* __restrict__ out)
{
    const int t = threadIdx.x, w = t >> 6, l = t & 63;
    const int row = blockIdx.x * 4 + w;
    const f16* hr = h2 + (size_t)row * 128;
    float s = (float)hr[l] * W3[l] + (float)hr[64 + l] * W3[64 + l];
    #pragma unroll
    for (int m = 1; m < 64; m <<= 1) s += __shfl_xor(s, m);
    if (l == 0) out[row] = s + b3[0];
}

// ============================================================================
extern "C" void kernel_launch(void* const* d_in, const int* in_sizes, int n_in,
                              void* d_out, int out_size, void* d_ws, size_t ws_size,
                              hipStream_t stream)
{
    const float* anchor = (const float*)d_in[0];
    const float* guess  = (const float*)d_in[1];
    const float* Wa = (const float*)d_in[2];
    const float* ba = (const float*)d_in[3];
    const float* Wg = (const float*)d_in[4];
    const float* bg = (const float*)d_in[5];
    const float* W1 = (const float*)d_in[6];
    const float* b1 = (const float*)d_in[7];
    const float* a1 = (const float*)d_in[8];
    const float* W2 = (const float*)d_in[9];
    const float* b2 = (const float*)d_in[10];
    const float* a2 = (const float*)d_in[11];
    const float* W3 = (const float*)d_in[12];
    const float* b3 = (const float*)d_in[13];
    float* out = (float*)d_out;
    char* ws = (char*)d_ws;

    const size_t MB = 1u << 20;
    // live through flash:
    f16* GE16 = (f16*)(ws + 0 * MB);                    // Q        4 MB
    f16* AC16 = (f16*)(ws + 4 * MB);                    // K        4 MB
    f16* VT16 = (f16*)(ws + 8 * MB);                    // V^T      4 MB
    // dead after projections (aliased later):
    f16* A16  = (f16*)(ws + 12 * MB);                   // anchor   4 MB
    f16* G16  = (f16*)(ws + 16 * MB);                   // guess    4 MB
    // weights:
    f16* WA16 = (f16*)(ws + 20 * MB);                   // 128 KB
    f16* WG16 = (f16*)(ws + 20 * MB + 128 * 1024);      // 128 KB
    f16* W116 = (f16*)(ws + 20 * MB + 256 * 1024);      // 384 KB
    f16* W216 = (f16*)(ws + 20 * MB + 640 * 1024);      // 64 KB
    float* MP = (float*)(ws + 21 * MB);                 // 8x8192 f32  256 KB
    float* LP = (float*)(ws + 21 * MB + 256 * 1024);    // 256 KB
    f16* OPN  = (f16*)(ws + 22 * MB);                   // 8x[8192][256] f16  32 MB
    // aliases (valid after flash):
    f16* DIS  = (f16*)(ws + 0 * MB);                    // [8192][768]  12 MB
    f16* H1   = (f16*)(ws + 12 * MB);                   // 4 MB
    f16* H2   = (f16*)(ws + 16 * MB);                   // 2 MB
    // max extent: 54 MB

    cvt_f32_f16<<<2048, 256, 0, stream>>>(anchor, A16, 524288);
    cvt_f32_f16<<<2048, 256, 0, stream>>>(guess,  G16, 524288);
    cvt_f32_f16<<<64,   256, 0, stream>>>(Wa, WA16, 16384);
    cvt_f32_f16<<<64,   256, 0, stream>>>(Wg, WG16, 16384);
    cvt_f32_f16<<<192,  256, 0, stream>>>(W1, W116, 49152);
    cvt_f32_f16<<<32,   256, 0, stream>>>(W2, W216, 8192);
    transpose_f16<<<dim3(256, 8), 256, 0, stream>>>(anchor, VT16);

    gemm_bt<0><<<dim3(64, 4), 256, 0, stream>>>(G16, WG16, bg, nullptr, GE16, 8192, 256, 256);
    gemm_bt<0><<<dim3(64, 4), 256, 0, stream>>>(A16, WA16, ba, nullptr, AC16, 8192, 256, 256);

    flash_attn<<<dim3(128, 8), 256, 0, stream>>>(GE16, AC16, VT16, OPN, MP, LP);

    build_dis<<<8192, 256, 0, stream>>>(guess, OPN, MP, LP, DIS);

    gemm_bt<1><<<dim3(64, 4), 256, 0, stream>>>(DIS, W116, b1, a1, H1, 8192, 256, 768);
    gemm_bt<1><<<dim3(64, 2), 256, 0, stream>>>(H1, W216, b2, a2, H2, 8192, 128, 256);
    final_dot<<<2048, 256, 0, stream>>>(H2, W3, b3, out);
}

// Round 4
// 180.347 us; speedup vs baseline: 2.6949x; 1.1877x over previous
//
#include <hip/hip_runtime.h>

// Round 4: round-3 design with cvt_pkrtz type fix (auto + bit_cast).
// Flash attention around 32x32x16 MFMA (32 q-rows/wave), XOR-swizzled LDS +
// global_load_lds (pre-swizzled global source, linear dest), cvt_pkrtz +
// permlane32_swap P-packing, defer-max, log2-domain softmax.

typedef _Float16 f16;
typedef _Float16 h8_t  __attribute__((ext_vector_type(8)));
typedef _Float16 h4_t  __attribute__((ext_vector_type(4)));
typedef float    f4_t  __attribute__((ext_vector_type(4)));
typedef float    f16x  __attribute__((ext_vector_type(16)));
typedef unsigned int u4_t  __attribute__((ext_vector_type(4)));

#define LOG2E 1.4426950408889634f

__device__ __forceinline__ void llds16(const f16* g, f16* s) {
    __builtin_amdgcn_global_load_lds(
        (const __attribute__((address_space(1))) void*)g,
        (__attribute__((address_space(3))) void*)s, 16, 0, 0);
}
__device__ __forceinline__ unsigned int pk2(float a, float b) {
    auto h = __builtin_amdgcn_cvt_pkrtz(a, b);   // __fp16 ext_vector_type(2)
    return __builtin_bit_cast(unsigned int, h);
}

// ------------------------------------------------ weights f32->f16 (one kernel)
__global__ __launch_bounds__(256)
void cvt_weights(const float* __restrict__ Wa, const float* __restrict__ Wg,
                 const float* __restrict__ W1, const float* __restrict__ W2,
                 f16* __restrict__ oa, f16* __restrict__ og,
                 f16* __restrict__ o1, f16* __restrict__ o2)
{
    int i = blockIdx.x * 256 + threadIdx.x;   // quad index; total 90112
    const float* s; f16* d; int off;
    if (i < 16384)      { s = Wa; d = oa; off = i; }
    else if (i < 32768) { s = Wg; d = og; off = i - 16384; }
    else if (i < 81920) { s = W1; d = o1; off = i - 32768; }
    else                { s = W2; d = o2; off = i - 81920; }
    f4_t v = ((const f4_t*)s)[off];
    h4_t h;
    h[0] = (f16)v[0]; h[1] = (f16)v[1]; h[2] = (f16)v[2]; h[3] = (f16)v[3];
    ((h4_t*)d)[off] = h;
}

// ------------------------------------------------- transpose anchor -> Vt f16
__global__ __launch_bounds__(256)
void transpose_f16(const float* __restrict__ src, f16* __restrict__ dst)
{
    __shared__ float tile[32][33];
    const int kb = blockIdx.x, db = blockIdx.y;
    const int t  = threadIdx.x;
    const int ty = t >> 3, tx4 = (t & 7) * 4;
    f4_t v = *(const f4_t*)(src + (size_t)(kb * 32 + ty) * 256 + db * 32 + tx4);
    tile[ty][tx4 + 0] = v[0]; tile[ty][tx4 + 1] = v[1];
    tile[ty][tx4 + 2] = v[2]; tile[ty][tx4 + 3] = v[3];
    __syncthreads();
    h4_t h;
    h[0] = (f16)tile[tx4 + 0][ty]; h[1] = (f16)tile[tx4 + 1][ty];
    h[2] = (f16)tile[tx4 + 2][ty]; h[3] = (f16)tile[tx4 + 3][ty];
    *(h4_t*)(dst + (size_t)(db * 32 + ty) * 8192 + kb * 32 + tx4) = h;
}

// ------------------------------------------- C = scale*(A @ B^T + bias), PReLU
template<int ACT, int SRC32>
__global__ __launch_bounds__(256)
void gemm_bt(const void* __restrict__ A, const f16* __restrict__ B,
             const float* __restrict__ bias, const float* __restrict__ act_a,
             float scale, f16* __restrict__ C, int M, int N, int K)
{
    constexpr int BM = 128, BN = 64, BK = 32, LDA = 40, LDB = 40;
    __shared__ f16 As[BM * LDA];
    __shared__ f16 Bs[BN * LDB];
    const int t = threadIdx.x;
    const int w = t >> 6, l = t & 63, lg = l >> 4, lr = l & 15;
    const int wm = w >> 1, wn = w & 1;
    const int bm = blockIdx.x, bn = blockIdx.y;
    f4_t acc[4][2] = {};

    for (int kt = 0; kt < K; kt += BK) {
        #pragma unroll
        for (int i = 0; i < 2; i++) {
            int s = t + i * 256;
            int row = s >> 2, c8 = (s & 3) * 8;
            if constexpr (SRC32) {
                const float* Af = (const float*)A + (size_t)(bm * BM + row) * K + kt + c8;
                f4_t v0 = *(const f4_t*)Af;
                f4_t v1 = *(const f4_t*)(Af + 4);
                h8_t h;
                h[0]=(f16)v0[0]; h[1]=(f16)v0[1]; h[2]=(f16)v0[2]; h[3]=(f16)v0[3];
                h[4]=(f16)v1[0]; h[5]=(f16)v1[1]; h[6]=(f16)v1[2]; h[7]=(f16)v1[3];
                *(h8_t*)(&As[row * LDA + c8]) = h;
            } else {
                *(u4_t*)(&As[row * LDA + c8]) =
                    *(const u4_t*)((const f16*)A + (size_t)(bm * BM + row) * K + kt + c8);
            }
        }
        {
            int row = t >> 2, c8 = (t & 3) * 8;
            *(u4_t*)(&Bs[row * LDB + c8]) =
                *(const u4_t*)(B + (size_t)(bn * BN + row) * K + kt + c8);
        }
        __syncthreads();
        h8_t af[4], bf[2];
        #pragma unroll
        for (int mf = 0; mf < 4; mf++)
            af[mf] = *(const h8_t*)(&As[(wm * 64 + mf * 16 + lr) * LDA + lg * 8]);
        #pragma unroll
        for (int nf = 0; nf < 2; nf++)
            bf[nf] = *(const h8_t*)(&Bs[(wn * 32 + nf * 16 + lr) * LDB + lg * 8]);
        #pragma unroll
        for (int mf = 0; mf < 4; mf++)
            #pragma unroll
            for (int nf = 0; nf < 2; nf++)
                acc[mf][nf] = __builtin_amdgcn_mfma_f32_16x16x32_f16(
                    af[mf], bf[nf], acc[mf][nf], 0, 0, 0);
        __syncthreads();
    }

    float av = 0.f;
    if constexpr (ACT) av = *act_a;
    #pragma unroll
    for (int mf = 0; mf < 4; mf++)
        #pragma unroll
        for (int nf = 0; nf < 2; nf++)
            #pragma unroll
            for (int r = 0; r < 4; r++) {
                int row = bm * BM + wm * 64 + mf * 16 + lg * 4 + r;
                int col = bn * BN + wn * 32 + nf * 16 + lr;
                float v = (acc[mf][nf][r] + bias[col]) * scale;
                if constexpr (ACT) v = v > 0.f ? v : av * v;
                C[(size_t)row * N + col] = (f16)v;
            }
}

// ------------------------------------------------------------- flash attention
// Q pre-scaled by log2(e). 512 blocks: sl = bid&7 (XCD-pinned KV slice),
// qb = bid>>3. 4 waves x 32 q-rows = 128 q/block. KVBLK=64, 16 tiles/slice.
__global__ __launch_bounds__(256, 2)
void flash_attn(const f16* __restrict__ Q, const f16* __restrict__ Kc,
                const f16* __restrict__ Vt, f16* __restrict__ OPN,
                float* __restrict__ mpart, float* __restrict__ lpart)
{
    constexpr int D = 256, BK = 64, NK = 8192, SL = 1024, NT = SL / BK;
    __shared__ f16 Ks[BK * D];    // 32 KB
    __shared__ f16 Vs[D * BK];    // 32 KB
    const int t = threadIdx.x, w = t >> 6, l = t & 63;
    const int q = l & 31, hi = l >> 5;
    const int sl = blockIdx.x & 7, qb = blockIdx.x >> 3;
    const int k0b = sl * SL;
    const int qg0 = qb * 128 + w * 32;

    // Q fragments (global, row-strided; once per block)
    h8_t qf[16];
    {
        const f16* qr = Q + (size_t)(qg0 + q) * D + hi * 8;
        #pragma unroll
        for (int ks = 0; ks < 16; ks++) qf[ks] = *(const h8_t*)(qr + ks * 16);
    }

    // staging lane constants (inverse-swizzled source addressing)
    const int sK0 = ((t & 31) ^ (t >> 5)) << 3;     // K col element, i even
    const int sx  = (t & 15) ^ (t >> 4);
    const int dV  = (t >> 4) * 2 + (sx >> 3);       // V source row offset in 32
    const int cV  = (sx & 7) << 3;                  // V source col element

    auto stageK = [&](int k0) {
        #pragma unroll
        for (int i = 0; i < 8; i++) {
            const f16* g = Kc + (size_t)(k0 + i * 8 + (t >> 5)) * D + (sK0 ^ ((i & 1) << 6));
            llds16(g, &Ks[i * 2048 + w * 512]);
        }
    };
    auto stageV = [&](int k0) {
        #pragma unroll
        for (int i = 0; i < 8; i++) {
            const f16* g = Vt + (size_t)(i * 32 + dV) * NK + k0 + cV;
            llds16(g, &Vs[i * 2048 + w * 512]);
        }
    };

    stageK(k0b); stageV(k0b);
    __syncthreads();

    f16x o[8] = {};
    f16x sa0, sa1;
    float m_run = -1e30f, l_run = 0.f;
    const int rswzK = (q & 15) << 4;
    const int kbase0 = q * 512;
    const int vbase  = (q >> 1) * 256;
    const int vswz   = (q >> 1) << 4;
    const int vcol0  = ((q & 1) << 7) | (hi << 4);

    for (int kv = 0; kv < NT; ++kv) {
        // ---- QK^T (swapped): sa[m=key][n=q]
        #pragma unroll
        for (int r = 0; r < 16; r++) { sa0[r] = 0.f; sa1[r] = 0.f; }
        #pragma unroll
        for (int ks = 0; ks < 16; ks++) {
            const int cb = ((ks * 32) | (hi << 4)) ^ rswzK;
            h8_t a0 = *(const h8_t*)((const char*)Ks + kbase0 + cb);
            h8_t a1 = *(const h8_t*)((const char*)Ks + kbase0 + 16384 + cb);
            sa0 = __builtin_amdgcn_mfma_f32_32x32x16_f16(a0, qf[ks], sa0, 0, 0, 0);
            sa1 = __builtin_amdgcn_mfma_f32_32x32x16_f16(a1, qf[ks], sa1, 0, 0, 0);
        }

        // ---- online softmax, log2 domain
        float mt = sa0[0];
        #pragma unroll
        for (int r = 1; r < 16; r++) mt = fmaxf(mt, sa0[r]);
        #pragma unroll
        for (int r = 0; r < 16; r++) mt = fmaxf(mt, sa1[r]);
        mt = fmaxf(mt, __shfl_xor(mt, 32));
        if (!__all(mt <= m_run + 8.0f)) {            // defer-max (T13)
            const float mnew = fmaxf(m_run, mt);
            const float corr = exp2f(m_run - mnew);
            #pragma unroll
            for (int r = 0; r < 16; r++) {
                const float c = __shfl(corr, (r & 3) + 8 * (r >> 2) + 4 * hi);
                #pragma unroll
                for (int nb = 0; nb < 8; nb++) o[nb][r] *= c;
            }
            l_run *= corr;
            m_run = mnew;
        }
        float rs = 0.f;
        #pragma unroll
        for (int r = 0; r < 16; r++) { sa0[r] = exp2f(sa0[r] - m_run); rs += sa0[r]; }
        #pragma unroll
        for (int r = 0; r < 16; r++) { sa1[r] = exp2f(sa1[r] - m_run); rs += sa1[r]; }
        rs += __shfl_xor(rs, 32);
        l_run += rs;

        __syncthreads();                              // all waves done reading K
        if (kv + 1 < NT) stageK(k0b + (kv + 1) * BK); // in flight across PV

        // ---- PV: A = P (packed in-register), B = V from swizzled LDS
        #pragma unroll
        for (int kb = 0; kb < 2; kb++) {
            const f16x& P = kb ? sa1 : sa0;
            #pragma unroll
            for (int s = 0; s < 2; s++) {
                unsigned int w00 = pk2(P[8*s+0], P[8*s+1]);
                unsigned int w01 = pk2(P[8*s+2], P[8*s+3]);
                unsigned int w10 = pk2(P[8*s+4], P[8*s+5]);
                unsigned int w11 = pk2(P[8*s+6], P[8*s+7]);
                asm volatile("v_permlane32_swap_b32 %0, %1" : "+v"(w00), "+v"(w10));
                asm volatile("v_permlane32_swap_b32 %0, %1" : "+v"(w01), "+v"(w11));
                u4_t up; up[0] = w00; up[1] = w01; up[2] = w10; up[3] = w11;
                const h8_t apv = __builtin_bit_cast(h8_t, up);
                const int S = kb * 2 + s;
                const int cb = (vcol0 | (S << 5)) ^ vswz;
                #pragma unroll
                for (int nb = 0; nb < 8; nb++) {
                    h8_t bf = *(const h8_t*)((const char*)Vs + nb * 4096 + vbase + cb);
                    o[nb] = __builtin_amdgcn_mfma_f32_32x32x16_f16(apv, bf, o[nb], 0, 0, 0);
                }
            }
        }
        __syncthreads();                              // all waves done reading V
        if (kv + 1 < NT) stageV(k0b + (kv + 1) * BK); // in flight across next QK
    }

    // ---- normalized f16 partial O + (m, l) per slice
    #pragma unroll
    for (int r = 0; r < 16; r++) {
        const int qr = (r & 3) + 8 * (r >> 2) + 4 * hi;
        const float linv = 1.0f / __shfl(l_run, qr);
        const size_t rowoff = ((size_t)sl * NK + qg0 + qr) * D;
        #pragma unroll
        for (int nb = 0; nb < 8; nb++)
            OPN[rowoff + nb * 32 + q] = (f16)(o[nb][r] * linv);
    }
    if (hi == 0) {
        mpart[(size_t)sl * NK + qg0 + q] = m_run;
        lpart[(size_t)sl * NK + qg0 + q] = l_run;
    }
}

// ------------------------------- combine 8 slice partials, build dis_x (f16)
__global__ __launch_bounds__(256)
void build_dis(const float* __restrict__ guess, const f16* __restrict__ OPN,
               const float* __restrict__ mp, const float* __restrict__ lp,
               f16* __restrict__ dis)
{
    const int m = blockIdx.x, d = threadIdx.x;
    float M = -3.0e38f;
    #pragma unroll
    for (int s = 0; s < 8; s++) M = fmaxf(M, mp[s * 8192 + m]);
    float wsum = 0.f, num = 0.f;
    #pragma unroll
    for (int s = 0; s < 8; s++) {
        float c = exp2f(mp[s * 8192 + m] - M) * lp[s * 8192 + m];  // log2 domain
        wsum += c;
        num  += c * (float)OPN[((size_t)s * 8192 + m) * 256 + d];
    }
    const float v = num / wsum;
    const float g = guess[(size_t)m * 256 + d];
    dis[(size_t)m * 768 + d]       = (f16)g;
    dis[(size_t)m * 768 + 256 + d] = (f16)v;
    dis[(size_t)m * 768 + 512 + d] = (f16)(g - v);
}

// ------------------------------------------------------ out = h2 @ W3^T + b3
__global__ __launch_bounds__(256)
void final_dot(const f16* __restrict__ h2, const float* __restrict__ W3,
               const float* __restrict__ b3, float* __restrict__ out)
{
    const int t = threadIdx.x, w = t >> 6, l = t & 63;
    const int row = blockIdx.x * 4 + w;
    const f16* hr = h2 + (size_t)row * 128;
    float s = (float)hr[l] * W3[l] + (float)hr[64 + l] * W3[64 + l];
    #pragma unroll
    for (int m = 1; m < 64; m <<= 1) s += __shfl_xor(s, m);
    if (l == 0) out[row] = s + b3[0];
}

// ============================================================================
extern "C" void kernel_launch(void* const* d_in, const int* in_sizes, int n_in,
                              void* d_out, int out_size, void* d_ws, size_t ws_size,
                              hipStream_t stream)
{
    const float* anchor = (const float*)d_in[0];
    const float* guess  = (const float*)d_in[1];
    const float* Wa = (const float*)d_in[2];
    const float* ba = (const float*)d_in[3];
    const float* Wg = (const float*)d_in[4];
    const float* bg = (const float*)d_in[5];
    const float* W1 = (const float*)d_in[6];
    const float* b1 = (const float*)d_in[7];
    const float* a1 = (const float*)d_in[8];
    const float* W2 = (const float*)d_in[9];
    const float* b2 = (const float*)d_in[10];
    const float* a2 = (const float*)d_in[11];
    const float* W3 = (const float*)d_in[12];
    const float* b3 = (const float*)d_in[13];
    float* out = (float*)d_out;
    char* ws = (char*)d_ws;

    const size_t MB = 1u << 20;
    f16* GE16 = (f16*)(ws + 0 * MB);                    // Q (x log2e)  4 MB
    f16* AC16 = (f16*)(ws + 4 * MB);                    // K            4 MB
    f16* VT16 = (f16*)(ws + 8 * MB);                    // V^T          4 MB
    f16* OPN  = (f16*)(ws + 12 * MB);                   // 8x[8192][256] 32 MB
    f16* WA16 = (f16*)(ws + 44 * MB);
    f16* WG16 = (f16*)(ws + 44 * MB + 128 * 1024);
    f16* W116 = (f16*)(ws + 44 * MB + 256 * 1024);
    f16* W216 = (f16*)(ws + 44 * MB + 640 * 1024);
    float* MP = (float*)(ws + 45 * MB);                 // 256 KB
    float* LP = (float*)(ws + 45 * MB + 256 * 1024);    // 256 KB
    // aliases after flash / build_dis:
    f16* DIS  = (f16*)(ws + 0 * MB);                    // 12 MB (over Q/K/V)
    f16* H1   = (f16*)(ws + 12 * MB);                   // 4 MB  (over OPN, dead)
    f16* H2   = (f16*)(ws + 16 * MB);                   // 2 MB

    cvt_weights<<<352, 256, 0, stream>>>(Wa, Wg, W1, W2, WA16, WG16, W116, W216);
    transpose_f16<<<dim3(256, 8), 256, 0, stream>>>(anchor, VT16);

    gemm_bt<0, 1><<<dim3(64, 4), 256, 0, stream>>>(guess,  WG16, bg, nullptr, LOG2E, GE16, 8192, 256, 256);
    gemm_bt<0, 1><<<dim3(64, 4), 256, 0, stream>>>(anchor, WA16, ba, nullptr, 1.0f,  AC16, 8192, 256, 256);

    flash_attn<<<512, 256, 0, stream>>>(GE16, AC16, VT16, OPN, MP, LP);

    build_dis<<<8192, 256, 0, stream>>>(guess, OPN, MP, LP, DIS);

    gemm_bt<1, 0><<<dim3(64, 4), 256, 0, stream>>>(DIS, W116, b1, a1, 1.0f, H1, 8192, 256, 768);
    gemm_bt<1, 0><<<dim3(64, 2), 256, 0, stream>>>(H1,  W216, b2, a2, 1.0f, H2, 8192, 128, 256);
    final_dot<<<2048, 256, 0, stream>>>(H2, W3, b3, out);
}